// Round 8
// baseline (887.603 us; speedup 1.0000x reference)
//
#include <hip/hip_runtime.h>
#include <math.h>

typedef unsigned int u32;
typedef unsigned long long u64;
typedef short s16x8 __attribute__((ext_vector_type(8)));
typedef float f32x4 __attribute__((ext_vector_type(4)));

#define HH 128
#define WW 128
#define NPIX (128*128)
#define NANCH (NPIX*6)
#define KPRE 6000
#define KPOST 300
#define SORT_CAP 16384
#define RW 96
#define NMS_T 0.7f
#define BROWS 8

#define OUT_PROB 1500
#define OUT_BBOX (1500 + 98304)

/* ---------------- ws layout (bytes) ----------------
   [conv1 33.5M][Xth 33.5M|Xtl 33.5M][Wph 9.4M|Wpl 9.4M] = 119.5MB
   post-conv3 buffers alias offset 33.5MB. */
#define WS_CONV1 ((size_t)0)
#define WS_XTH   ((size_t)33554432)
#define WS_WPH   ((size_t)100663296)
#define WS_BOXES ((size_t)33554432)
#define WS_SCORE (WS_BOXES + 1572864)
#define WS_KEYS  (WS_SCORE + 393216)
#define WS_TB    (WS_KEYS + 131072)
#define WS_AREA  (WS_TB + 98304)
#define WS_SUP   (WS_AREA + 24576)
#define WS_HIST  (WS_SUP + 4718592)
#define WS_CTRL  (WS_HIST + 262144)
#define WS_KEEP  (WS_CTRL + 256)
#define WS_DIAG  (WS_KEEP + 1280)

__device__ __forceinline__ unsigned short f2bf(float x) {
    u32 b = __float_as_uint(x);
    u32 r = (b + 0x7FFFu + ((b >> 16) & 1u)) >> 16;
    return (unsigned short)r;
}

/* async global->LDS, 16B/lane: dest = wave-uniform base + lane*16 */
__device__ __forceinline__ void gl_lds16(const void* g, void* l) {
    __builtin_amdgcn_global_load_lds(
        (__attribute__((address_space(1))) const void*)g,
        (__attribute__((address_space(3))) void*)l,
        16, 0, 0);
}

/* X prepass: in[c][pix] f32 -> Xth[pix][c], Xtl[pix][c] bf16 (transpose+split) */
__global__ __launch_bounds__(256) void k_xsplit(const float* __restrict__ in,
                                                unsigned short* __restrict__ xth) {
    unsigned short* xtl = xth + 16777216;
    __shared__ unsigned short Th[64][72];
    __shared__ unsigned short Tl[64][72];
    const int px0 = blockIdx.x * 64;   /* 256 */
    const int c0  = blockIdx.y * 64;   /* 16  */
    const int t = threadIdx.x;
    const int r = t >> 4;
    const int p4 = (t & 15) * 4;
#pragma unroll
    for (int i = 0; i < 4; ++i) {
        int cr = r + 16 * i;
        float4 v = *(const float4*)(in + (size_t)(c0 + cr) * NPIX + px0 + p4);
        float vv[4] = {v.x, v.y, v.z, v.w};
#pragma unroll
        for (int k = 0; k < 4; ++k) {
            unsigned short h = f2bf(vv[k]);
            float hf = __uint_as_float((u32)h << 16);
            unsigned short l = f2bf(vv[k] - hf);
            Th[p4 + k][cr] = h;
            Tl[p4 + k][cr] = l;
        }
    }
    __syncthreads();
    const int p = t >> 2, q = t & 3;
    unsigned short* dh = xth + (size_t)(px0 + p) * 1024 + c0 + q * 16;
    unsigned short* dl = xtl + (size_t)(px0 + p) * 1024 + c0 + q * 16;
    *(uint4*)dh       = *(const uint4*)&Th[p][q * 16];
    *(uint4*)(dh + 8) = *(const uint4*)&Th[p][q * 16 + 8];
    *(uint4*)dl       = *(const uint4*)&Tl[p][q * 16];
    *(uint4*)(dl + 8) = *(const uint4*)&Tl[p][q * 16 + 8];
}

/* W prepass: w[oc][c*9+tap] -> Wph[tap][oc][c], Wpl[...] bf16; + zero-stash */
__global__ __launch_bounds__(256) void k_wpack(const float* __restrict__ w,
                                               unsigned short* __restrict__ wph,
                                               float* __restrict__ zstash) {
    if (blockIdx.x == 0 && threadIdx.x < 128) zstash[threadIdx.x] = 0.f;
    int id = blockIdx.x * 256 + threadIdx.x;     /* 524288 = oc*1024 + c */
    int oc = id >> 10, c = id & 1023;
    const float* src = w + (size_t)oc * 9216 + c * 9;
#pragma unroll
    for (int tap = 0; tap < 9; ++tap) {
        float x = src[tap];
        unsigned short h = f2bf(x);
        unsigned short l = f2bf(x - __uint_as_float((u32)h << 16));
        wph[(size_t)tap * 524288 + id] = h;
        wph[4718592 + (size_t)tap * 524288 + id] = l;
    }
}

/* conv3 via MFMA, tap-major. PROVEN r4 version (399us, MfmaUtil 56, 0 confl):
   128oc x 128px block, 4 waves, 512-block 1D grid with bijective XCD remap
   (per-XCD X working set 9.2MB). SETTLED: r1 (32x32+W-reg), r2 (counted
   vmcnt), r5 (wide-wave 1/CU) all regressed; this 2-wave/SIMD 2-barrier
   structure is the local optimum. Do not touch. */
__global__ __launch_bounds__(256, 2) void k_conv3m(const unsigned short* __restrict__ xt,
                                                   const unsigned short* __restrict__ wp,
                                                   const float* __restrict__ bias,
                                                   const unsigned short* __restrict__ zst,
                                                   float* __restrict__ out) {
    const int bid = blockIdx.x;          /* 0..511 */
    const int xcd = bid & 7;
    const int kk  = bid >> 3;            /* 0..63 */
    const int ocg = kk & 3;
    const int y   = xcd * 16 + (kk >> 2);
    const int oc0 = ocg * 128;
    const int tid = threadIdx.x;
    const int lane = tid & 63;
    const int w    = tid >> 6;
    const int l15  = lane & 15;
    const int quad = lane >> 4;
    const int hoc  = w >> 1, hpx = w & 1;

    __shared__ __align__(16) unsigned short Lds[32768];   /* 64 KB */

    /* DMA slot geometry (per wave: 4 X slots + 4 W slots) */
    const int lg  = lane & 3;            /* LDS granule this lane fills  */
    const int lr  = lane >> 2;           /* row-within-16 this lane fills */

    const unsigned short* xsrc[4];
    int xstep[4];
    const unsigned short* wsrc[4];

    /* W sources: tap-linear, never redirected */
    int wp_pl[4], wp_ocr[4], wp_gs[4];
#pragma unroll
    for (int j = 0; j < 4; ++j) {
        int i = w + 4 * j;
        wp_pl[j]  = i >> 3;
        wp_ocr[j] = (i & 7) * 16 + lr;
        wp_gs[j]  = lg ^ ((wp_ocr[j] >> 1) & 3);
    }
    int xp_pl[4], xp_p[4], xp_gs[4];
#pragma unroll
    for (int j = 0; j < 4; ++j) {
        int i = w + 4 * j;
        xp_pl[j] = i >> 3;
        xp_p[j]  = (i & 7) * 16 + lr;
        xp_gs[j] = lg ^ ((xp_p[j] >> 1) & 3);
    }

    auto set_tap = [&](int tap) {
        int dy = tap / 3, dx = tap - dy * 3;
        int yy = y + dy - 1;
        bool yok = (yy >= 0) && (yy < HH);
#pragma unroll
        for (int j = 0; j < 4; ++j) {
            int x = dx - 1 + xp_p[j];
            bool ok = yok && (x >= 0) && (x < WW);
            xsrc[j] = ok ? xt + (size_t)xp_pl[j] * 16777216
                              + (size_t)(yy * WW + x) * 1024 + xp_gs[j] * 8
                         : zst + lg * 8;
            xstep[j] = ok ? 32 : 0;
        }
#pragma unroll
        for (int j = 0; j < 4; ++j)
            wsrc[j] = wp + (size_t)wp_pl[j] * 4718592 + (size_t)tap * 524288
                        + (size_t)(oc0 + wp_ocr[j]) * 1024 + wp_gs[j] * 8;
    };

    auto issue = [&](int sel) {
        const int bo = sel * 16384;
#pragma unroll
        for (int j = 0; j < 4; ++j) {
            gl_lds16(xsrc[j], &Lds[bo + (w + 4 * j) * 512]);
            xsrc[j] += xstep[j];
        }
#pragma unroll
        for (int j = 0; j < 4; ++j) {
            gl_lds16(wsrc[j], &Lds[bo + 8192 + (w + 4 * j) * 512]);
            wsrc[j] += 32;
        }
    };

    /* compute-side read bases: swizzle g identical for all og/nt (stride 16) */
    const int g  = quad ^ ((l15 >> 1) & 3);
    const int bB0 = (hpx * 64 + l15) * 32 + g * 8;
    const int bA0 = 8192 + (hoc * 64 + l15) * 32 + g * 8;

    f32x4 acc[4][4];
#pragma unroll
    for (int og = 0; og < 4; ++og)
#pragma unroll
        for (int nt = 0; nt < 4; ++nt) acc[og][nt] = (f32x4){0.f, 0.f, 0.f, 0.f};

    set_tap(0);
    issue(0);

    for (int s = 0; s < 288; ++s) {
        const int cur = s & 1;
        __syncthreads();        /* drains cur-buffer DMA (in flight one full
                                   stage) + all waves done with other buffer */
        if (s + 1 < 288) {
            int s1 = s + 1;
            if ((s1 & 31) == 0) set_tap(s1 >> 5);
            issue(s1 & 1);
        }

        const int bo = cur * 16384;
        s16x8 ah[4], al[4];
#pragma unroll
        for (int og = 0; og < 4; ++og) {
            ah[og] = *(const s16x8*)&Lds[bo + bA0 + og * 512];
            al[og] = *(const s16x8*)&Lds[bo + bA0 + 4096 + og * 512];
        }
#pragma unroll
        for (int nt = 0; nt < 4; ++nt) {
            const s16x8 bh = *(const s16x8*)&Lds[bo + bB0 + nt * 512];
            const s16x8 bl = *(const s16x8*)&Lds[bo + bB0 + 4096 + nt * 512];
#pragma unroll
            for (int og = 0; og < 4; ++og) {
                acc[og][nt] = __builtin_amdgcn_mfma_f32_16x16x32_bf16(ah[og], bh, acc[og][nt], 0, 0, 0);
                acc[og][nt] = __builtin_amdgcn_mfma_f32_16x16x32_bf16(ah[og], bl, acc[og][nt], 0, 0, 0);
                acc[og][nt] = __builtin_amdgcn_mfma_f32_16x16x32_bf16(al[og], bh, acc[og][nt], 0, 0, 0);
            }
        }
    }

    /* epilogue: D row(oc) = quad*4+reg, col(px) = l15 */
#pragma unroll
    for (int og = 0; og < 4; ++og) {
#pragma unroll
        for (int nt = 0; nt < 4; ++nt) {
#pragma unroll
            for (int rg = 0; rg < 4; ++rg) {
                const int oc = oc0 + hoc * 64 + og * 16 + quad * 4 + rg;
                const int px = hpx * 64 + nt * 16 + l15;
                float v = acc[og][nt][rg] + bias[oc];
                out[(size_t)oc * NPIX + y * WW + px] = fmaxf(v, 0.f);
            }
        }
    }
}

/* ---------------- fused 1x1 convs + pair softmax + pipeline-state init ---- */
__global__ __launch_bounds__(256) void k_conv1(const float* __restrict__ conv1,
                                               const float* __restrict__ wcls,
                                               const float* __restrict__ bcls,
                                               const float* __restrict__ wbox,
                                               const float* __restrict__ bboxb,
                                               float* __restrict__ out,
                                               u32* __restrict__ hist,
                                               u32* __restrict__ ctrl,
                                               u64* __restrict__ keys) {
    const int tid = threadIdx.x;
    {
        int gt = blockIdx.x * 256 + tid;
        hist[gt] = 0u;
        if (gt < 64) ctrl[gt] = 0u;
        if (gt < SORT_CAP) keys[gt] = ~0ULL;
    }
    const int og = tid >> 4, pg = tid & 15;
    const int px0 = blockIdx.x * 64;
    __shared__ __align__(16) float Wl[32][32];
    __shared__ __align__(16) float Xl[32][64];
    __shared__ float Sc[6][64];

    float a0[4] = {0, 0, 0, 0}, a1[4] = {0, 0, 0, 0};

    for (int cc = 0; cc < 16; ++cc) {
        {
            int u = tid;
            int row = (u * 4) >> 5;
            int col = (u * 4) & 31;
            float4 v;
            if (row < 6)       v = *(const float4*)(wcls + row * 512 + cc * 32 + col);
            else if (row < 30) v = *(const float4*)(wbox + (row - 6) * 512 + cc * 32 + col);
            else               v = make_float4(0.f, 0.f, 0.f, 0.f);
            *(float4*)&Wl[row][col] = v;
        }
        for (int u = tid; u < 512; u += 256) {
            int row = (u * 4) >> 6, col = (u * 4) & 63;
            *(float4*)&Xl[row][col] =
                *(const float4*)(conv1 + (size_t)(cc * 32 + row) * NPIX + px0 + col);
        }
        __syncthreads();
#pragma unroll
        for (int cp = 0; cp < 32; ++cp) {
            const float4 x = *(const float4*)&Xl[cp][pg * 4];
            const float w0 = Wl[og][cp];
            const float w1 = Wl[og + 16][cp];
            a0[0] = fmaf(w0, x.x, a0[0]); a0[1] = fmaf(w0, x.y, a0[1]);
            a0[2] = fmaf(w0, x.z, a0[2]); a0[3] = fmaf(w0, x.w, a0[3]);
            a1[0] = fmaf(w1, x.x, a1[0]); a1[1] = fmaf(w1, x.y, a1[1]);
            a1[2] = fmaf(w1, x.z, a1[2]); a1[3] = fmaf(w1, x.w, a1[3]);
        }
        __syncthreads();
    }
    const int pxb = px0 + pg * 4;
    if (og < 6) {
        const float bc = bcls[og];
#pragma unroll
        for (int kk = 0; kk < 4; ++kk) Sc[og][pg * 4 + kk] = a0[kk] + bc;
    } else {
        const float bb = bboxb[og - 6];
#pragma unroll
        for (int kk = 0; kk < 4; ++kk)
            out[OUT_BBOX + (size_t)(og - 6) * NPIX + pxb + kk] = a0[kk] + bb;
    }
    if (og + 16 < 30) {
        const float bb = bboxb[og + 10];
#pragma unroll
        for (int kk = 0; kk < 4; ++kk)
            out[OUT_BBOX + (size_t)(og + 10) * NPIX + pxb + kk] = a1[kk] + bb;
    }
    __syncthreads();
    if (og < 6) {
        const int pa = og < 3 ? og + 3 : og - 3;
#pragma unroll
        for (int kk = 0; kk < 4; ++kk) {
            const float s = Sc[og][pg * 4 + kk], sp = Sc[pa][pg * 4 + kk];
            out[OUT_PROB + (size_t)og * NPIX + pxb + kk] = 1.0f / (1.0f + expf(sp - s));
        }
    }
}

/* ---------------- anchor decode + clip + fused histogram ---------------- */
__global__ void k_decode(const float* __restrict__ out, const float* __restrict__ meta,
                         float4* __restrict__ boxes, float* __restrict__ scores,
                         u32* __restrict__ hist) {
#pragma clang fp contract(off)
    int t = blockIdx.x * blockDim.x + threadIdx.x;
    if (t >= NANCH) return;
    int a = t >> 14;
    int pix = t & 16383;
    int yc = pix >> 7, xc = pix & 127;
    int n = pix * 6 + a;
    float sc = out[OUT_PROB + (size_t)a * NPIX + pix];
    float d0 = out[OUT_BBOX + (size_t)(a * 4 + 0) * NPIX + pix];
    float d1 = out[OUT_BBOX + (size_t)(a * 4 + 1) * NPIX + pix];
    float d2 = out[OUT_BBOX + (size_t)(a * 4 + 2) * NPIX + pix];
    float d3 = out[OUT_BBOX + (size_t)(a * 4 + 3) * NPIX + pix];
    const float dims = (float)(16 << a);
    const float cxa = (xc + 0.5f) * 16.f;
    const float cya = (yc + 0.5f) * 16.f;
    float pcx = d0 * dims + cxa;
    float pcy = d1 * dims + cya;
    float pw  = expf(d2) * dims;
    float ph  = expf(d3) * dims;
    float imh = meta[0], imw = meta[1];
    float x1 = fminf(fmaxf(pcx - 0.5f * pw, 0.f), imw);
    float y1 = fminf(fmaxf(pcy - 0.5f * ph, 0.f), imh);
    float x2 = fminf(fmaxf(pcx + 0.5f * pw, 0.f), imw);
    float y2 = fminf(fmaxf(pcy + 0.5f * ph, 0.f), imh);
    boxes[n] = make_float4(x1, y1, x2, y2);
    scores[n] = sc;
    atomicAdd(&hist[__float_as_uint(sc) >> 16], 1u);
}

/* Parallel threshold select (r7, proven). */
__global__ __launch_bounds__(256) void k_select(const u32* __restrict__ hist,
                                                u32* __restrict__ ctrl) {
    __shared__ u32 S[256];
    __shared__ u32 T[256];
    __shared__ u32 wsb, wabove;
    const int tid = threadIdx.x;
    const int lane = tid & 63, wv = tid >> 6;
    for (int k = 0; k < 64; ++k) {
        int sb = wv * 64 + k;
        uint4 v = *(const uint4*)(hist + (size_t)sb * 256 + lane * 4);
        u32 p = v.x + v.y + v.z + v.w;
#pragma unroll
        for (int d = 1; d < 64; d <<= 1)
            p += (u32)__shfl_xor((int)p, d);
        if (lane == 0) S[sb] = p;
    }
    __syncthreads();
    T[tid] = S[tid];
    __syncthreads();
#pragma unroll
    for (int d = 1; d < 256; d <<= 1) {          /* inclusive suffix sum */
        u32 v2 = T[tid] + ((tid + d < 256) ? T[tid + d] : 0u);
        __syncthreads();
        T[tid] = v2;
        __syncthreads();
    }
    {
        u32 above = T[tid] - S[tid];
        if (above < KPRE && above + S[tid] >= KPRE) { wsb = (u32)tid; wabove = above; }
    }
    __syncthreads();
    const int sb = (int)wsb;
    const u32 h = hist[(size_t)sb * 256 + tid];
    T[tid] = h;
    __syncthreads();
#pragma unroll
    for (int d = 1; d < 256; d <<= 1) {
        u32 v2 = T[tid] + ((tid + d < 256) ? T[tid + d] : 0u);
        __syncthreads();
        T[tid] = v2;
        __syncthreads();
    }
    u32 acc = wabove + (T[tid] - h);             /* count strictly above bucket */
    if (acc < KPRE && acc + h >= KPRE) {
        ctrl[1] = (u32)(sb * 256 + tid);
        ctrl[2] = acc;
    }
}

__global__ void k_compact(const float* __restrict__ scores, u32* __restrict__ ctrl,
                          u64* __restrict__ keys) {
    int t = blockIdx.x * blockDim.x + threadIdx.x;
    if (t >= NANCH) return;
    u32 bits = __float_as_uint(scores[t]);
    if ((bits >> 16) >= ctrl[1]) {
        u32 pos = atomicAdd(&ctrl[0], 1u);
        if (pos < SORT_CAP) keys[pos] = ((u64)(~bits) << 32) | (u32)t;
    }
}

__global__ __launch_bounds__(1024) void k_sort_local(u64* __restrict__ keys) {
    __shared__ u64 lds[8192];
    const int tid = threadIdx.x;
    u64* g = keys + blockIdx.x * 8192;
    for (int u = tid; u < 8192; u += 1024) lds[u] = g[u];
    __syncthreads();
    for (int k = 2; k <= 8192; k <<= 1) {
        for (int j = k >> 1; j > 0; j >>= 1) {
            for (int u = tid; u < 4096; u += 1024) {
                int i = ((u & ~(j - 1)) << 1) | (u & (j - 1));
                int l = i | j;
                bool up = (i & k) == 0;
                u64 x = lds[i], y2 = lds[l];
                if ((x > y2) == up) { lds[i] = y2; lds[l] = x; }
            }
            __syncthreads();
        }
    }
    for (int u = tid; u < 8192; u += 1024) g[u] = lds[u];
}

/* merge the two sorted 8192-halves AND gather boxes/areas in one pass */
__global__ void k_mergegather(const u64* __restrict__ keys,
                              const float4* __restrict__ boxes,
                              float4* __restrict__ tb, float* __restrict__ areas) {
#pragma clang fp contract(off)
    int i = blockIdx.x * blockDim.x + threadIdx.x;
    if (i >= KPRE) return;
    const u64* A = keys;
    const u64* B = keys + 8192;
    int lo = i > 8192 ? i - 8192 : 0;
    int hi = i < 8192 ? i : 8192;
    while (lo < hi) {
        int a = (lo + hi) >> 1;
        if (A[a] < B[i - a - 1]) lo = a + 1; else hi = a;
    }
    int a = lo, b = i - lo;
    u64 va = (a < 8192) ? A[a] : ~0ULL;
    u64 vb = (b < 8192) ? B[b] : ~0ULL;
    u64 v = va < vb ? va : vb;
    u32 n = (u32)(v & 0xFFFFFFFFULL);
    float4 bx = boxes[n];
    tb[i] = bx;
    areas[i] = fmaxf(bx.z - bx.x, 0.f) * fmaxf(bx.w - bx.y, 0.f);
}

/* Tiled bitmap NMS precompute (r8): 8 rows per block, 750 blocks.
   Old: 6000 blocks, each word-iteration re-reads tb/areas from L2 (~370MB
   L2 traffic, 24000 tiny waves, one scattered 8B store per ballot). New:
   row boxes broadcast from LDS; 64 tb[j]/areas[j] loads amortized over 8
   ballots (8x less traffic); lanes 0-7 batch the 8 stores per word into one
   instruction. 8-aligned row groups never straddle a 64-chunk => all rows
   share wd0 = i>>6; triangle skip + diag semantics identical to r4/r6.
   IoU expression order identical per (i,j) => bit-identical keep-set. */
__global__ __launch_bounds__(256) void k_bitmap(const float4* __restrict__ tb,
                                                const float* __restrict__ areas,
                                                u64* __restrict__ suppr,
                                                u64* __restrict__ diag) {
#pragma clang fp contract(off)
    const int i0 = blockIdx.x * BROWS;
    const int lane = threadIdx.x & 63;
    const int wv = threadIdx.x >> 6;
    __shared__ float4 rb[BROWS];
    __shared__ float  ra[BROWS];
    if (threadIdx.x < BROWS) {
        rb[threadIdx.x] = tb[i0 + threadIdx.x];
        ra[threadIdx.x] = areas[i0 + threadIdx.x];
    }
    __syncthreads();
    const int wd0 = i0 >> 6;
    for (int Wd = wd0 + wv; Wd < RW; Wd += 4) {
        const int j = Wd * 64 + lane;
        const bool jok = j < KPRE;
        float4 bj = make_float4(0.f, 0.f, 0.f, 0.f);
        float aj = 0.f;
        if (jok) { bj = tb[j]; aj = areas[j]; }
        u64 mymask = 0;
#pragma unroll
        for (int r = 0; r < BROWS; ++r) {
            const float4 bi = rb[r];
            const float ai = ra[r];
            bool sup = false;
            if (jok) {
                float iw = fmaxf(fminf(bi.z, bj.z) - fmaxf(bi.x, bj.x), 0.f);
                float ih = fmaxf(fminf(bi.w, bj.w) - fmaxf(bi.y, bj.y), 0.f);
                float inter = iw * ih;
                float denom = ((aj + ai) - inter) + 1e-9f;
                sup = (inter / denom) > NMS_T;
            }
            u64 m = __ballot(sup);
            if (lane == r) mymask = m;
        }
        if (lane < BROWS) {
            suppr[(size_t)(i0 + lane) * RW + Wd] = mymask;
            if (Wd == wd0) diag[i0 + lane] = mymask;
        }
    }
}

/* Chunked greedy scan (r6, proven) + fused ROI write (r7). */
__global__ void k_scan(const u64* __restrict__ suppr, const u64* __restrict__ diag,
                       const float4* __restrict__ tb, float* __restrict__ out) {
    const int lane = threadIdx.x;     /* 64 threads */
    __shared__ int keepL[KPOST];
    u64 a0 = (lane < 93) ? ~0ULL : (lane == 93 ? ((1ULL << 48) - 1) : 0ULL);
    const int w1 = lane + 64;
    u64 a1 = (w1 < 93) ? ~0ULL : (w1 == 93 ? ((1ULL << 48) - 1) : 0ULL);
    int kept = 0;
    u64 dv_cur = diag[lane];          /* chunk 0 diag, lane l = row l word 0 */
    for (int c = 0; c < 94 && kept < KPOST; ++c) {
        u64 dv_nxt = (c < 93) ? diag[(size_t)(c + 1) * 64 + lane] : 0ULL;
        u64 ac = (c < 64) ? (u64)__shfl((long long)a0, c)
                          : (u64)__shfl((long long)a1, c - 64);
        u64 m = ac;
        u64 keptMask = 0;
        while (m && kept < KPOST) {
            int b = __ffsll((long long)m) - 1;
            if (lane == 0) keepL[kept] = (c << 6) + b;
            kept++;
            keptMask |= (1ULL << b);
            u64 dv = (u64)__shfl((long long)dv_cur, b);
            m &= ~dv;
            m &= ~(1ULL << b);        /* self-advance (zero-area safe) */
        }
        if (keptMask && kept < KPOST + 64) {   /* apply rows to future words */
            u64 s0 = 0, s1 = 0;
            u64 km = keptMask;
            while (km) {
                int b = __ffsll((long long)km) - 1;
                km &= km - 1;
                const u64* row = suppr + (size_t)((c << 6) + b) * RW;
                u64 r0 = (lane > c) ? row[lane] : 0ULL;
                u64 r1 = (w1 > c && w1 < 94) ? row[w1] : 0ULL;
                s0 |= r0; s1 |= r1;
            }
            a0 &= ~s0; a1 &= ~s1;
        }
        dv_cur = dv_nxt;
    }
    __syncthreads();
    for (int r = lane; r < KPOST; r += 64) {
        float4 b = make_float4(0.f, 0.f, 0.f, 0.f);
        if (r < kept) b = tb[keepL[r]];
        out[r * 5 + 0] = 0.f;
        out[r * 5 + 1] = b.x;
        out[r * 5 + 2] = b.y;
        out[r * 5 + 3] = b.z;
        out[r * 5 + 4] = b.w;
    }
}

extern "C" void kernel_launch(void* const* d_in, const int* in_sizes, int n_in,
                              void* d_out, int out_size, void* d_ws, size_t ws_size,
                              hipStream_t stream) {
    (void)in_sizes; (void)n_in; (void)out_size; (void)ws_size;
    const float* x     = (const float*)d_in[0];
    const float* meta  = (const float*)d_in[1];
    const float* wc3   = (const float*)d_in[3];
    const float* bc3   = (const float*)d_in[4];
    const float* wcls  = (const float*)d_in[5];
    const float* bcls  = (const float*)d_in[6];
    const float* wbox  = (const float*)d_in[7];
    const float* bboxb = (const float*)d_in[8];
    float* out = (float*)d_out;
    char* ws = (char*)d_ws;

    float*  conv1  = (float*)(ws + WS_CONV1);
    float4* boxes  = (float4*)(ws + WS_BOXES);
    float*  scores = (float*)(ws + WS_SCORE);
    u64*    keys   = (u64*)(ws + WS_KEYS);
    float4* tb     = (float4*)(ws + WS_TB);
    float*  areas  = (float*)(ws + WS_AREA);
    u64*    suppr  = (u64*)(ws + WS_SUP);
    u32*    hist   = (u32*)(ws + WS_HIST);
    u32*    ctrl   = (u32*)(ws + WS_CTRL);
    u64*    diag   = (u64*)(ws + WS_DIAG);

    float* zstash = out;   /* 512B zeros; rewritten by k_scan at the end */

    unsigned short* xth = (unsigned short*)(ws + WS_XTH);
    unsigned short* wph = (unsigned short*)(ws + WS_WPH);
    k_xsplit<<<dim3(256, 16), 256, 0, stream>>>(x, xth);
    k_wpack<<<2048, 256, 0, stream>>>(wc3, wph, zstash);
    k_conv3m<<<512, 256, 0, stream>>>(xth, wph, bc3,
                                      (const unsigned short*)zstash, conv1);

    k_conv1<<<256, 256, 0, stream>>>(conv1, wcls, bcls, wbox, bboxb, out,
                                     hist, ctrl, keys);
    k_decode<<<384, 256, 0, stream>>>(out, meta, boxes, scores, hist);
    k_select<<<1, 256, 0, stream>>>(hist, ctrl);
    k_compact<<<384, 256, 0, stream>>>(scores, ctrl, keys);
    k_sort_local<<<2, 1024, 0, stream>>>(keys);
    k_mergegather<<<24, 256, 0, stream>>>(keys, boxes, tb, areas);
    k_bitmap<<<KPRE / BROWS, 256, 0, stream>>>(tb, areas, suppr, diag);
    k_scan<<<1, 64, 0, stream>>>(suppr, diag, tb, out);
}

// Round 10
// 871.972 us; speedup vs baseline: 1.0179x; 1.0179x over previous
//
#include <hip/hip_runtime.h>
#include <math.h>

typedef unsigned int u32;
typedef unsigned long long u64;
typedef short s16x8 __attribute__((ext_vector_type(8)));
typedef float f32x4 __attribute__((ext_vector_type(4)));

#define HH 128
#define WW 128
#define NPIX (128*128)
#define NANCH (NPIX*6)
#define KPRE 6000
#define KPOST 300
#define SORT_CAP 16384
#define RW 96
#define NMS_T 0.7f

#define OUT_PROB 1500
#define OUT_BBOX (1500 + 98304)

/* ---------------- ws layout (bytes) ----------------
   [conv1 33.5M][Xth 33.5M|Xtl 33.5M][Wph 9.4M|Wpl 9.4M] = 119.5MB
   post-conv3 buffers alias offset 33.5MB. */
#define WS_CONV1 ((size_t)0)
#define WS_XTH   ((size_t)33554432)
#define WS_WPH   ((size_t)100663296)
#define WS_BOXES ((size_t)33554432)
#define WS_SCORE (WS_BOXES + 1572864)
#define WS_KEYS  (WS_SCORE + 393216)
#define WS_TB    (WS_KEYS + 131072)
#define WS_AREA  (WS_TB + 98304)
#define WS_SUP   (WS_AREA + 24576)
#define WS_HIST  (WS_SUP + 4718592)
#define WS_CTRL  (WS_HIST + 262144)
#define WS_KEEP  (WS_CTRL + 256)
#define WS_DIAG  (WS_KEEP + 1280)

__device__ __forceinline__ unsigned short f2bf(float x) {
    u32 b = __float_as_uint(x);
    u32 r = (b + 0x7FFFu + ((b >> 16) & 1u)) >> 16;
    return (unsigned short)r;
}

/* async global->LDS, 16B/lane: dest = wave-uniform base + lane*16 */
__device__ __forceinline__ void gl_lds16(const void* g, void* l) {
    __builtin_amdgcn_global_load_lds(
        (__attribute__((address_space(1))) const void*)g,
        (__attribute__((address_space(3))) void*)l,
        16, 0, 0);
}

/* X prepass: in[c][pix] f32 -> Xth[pix][c], Xtl[pix][c] bf16 (transpose+split) */
__global__ __launch_bounds__(256) void k_xsplit(const float* __restrict__ in,
                                                unsigned short* __restrict__ xth) {
    unsigned short* xtl = xth + 16777216;
    __shared__ unsigned short Th[64][72];
    __shared__ unsigned short Tl[64][72];
    const int px0 = blockIdx.x * 64;   /* 256 */
    const int c0  = blockIdx.y * 64;   /* 16  */
    const int t = threadIdx.x;
    const int r = t >> 4;
    const int p4 = (t & 15) * 4;
#pragma unroll
    for (int i = 0; i < 4; ++i) {
        int cr = r + 16 * i;
        float4 v = *(const float4*)(in + (size_t)(c0 + cr) * NPIX + px0 + p4);
        float vv[4] = {v.x, v.y, v.z, v.w};
#pragma unroll
        for (int k = 0; k < 4; ++k) {
            unsigned short h = f2bf(vv[k]);
            float hf = __uint_as_float((u32)h << 16);
            unsigned short l = f2bf(vv[k] - hf);
            Th[p4 + k][cr] = h;
            Tl[p4 + k][cr] = l;
        }
    }
    __syncthreads();
    const int p = t >> 2, q = t & 3;
    unsigned short* dh = xth + (size_t)(px0 + p) * 1024 + c0 + q * 16;
    unsigned short* dl = xtl + (size_t)(px0 + p) * 1024 + c0 + q * 16;
    *(uint4*)dh       = *(const uint4*)&Th[p][q * 16];
    *(uint4*)(dh + 8) = *(const uint4*)&Th[p][q * 16 + 8];
    *(uint4*)dl       = *(const uint4*)&Tl[p][q * 16];
    *(uint4*)(dl + 8) = *(const uint4*)&Tl[p][q * 16 + 8];
}

/* W prepass: w[oc][c*9+tap] -> Wph[tap][oc][c], Wpl[...] bf16; + zero-stash */
__global__ __launch_bounds__(256) void k_wpack(const float* __restrict__ w,
                                               unsigned short* __restrict__ wph,
                                               float* __restrict__ zstash) {
    if (blockIdx.x == 0 && threadIdx.x < 128) zstash[threadIdx.x] = 0.f;
    int id = blockIdx.x * 256 + threadIdx.x;     /* 524288 = oc*1024 + c */
    int oc = id >> 10, c = id & 1023;
    const float* src = w + (size_t)oc * 9216 + c * 9;
#pragma unroll
    for (int tap = 0; tap < 9; ++tap) {
        float x = src[tap];
        unsigned short h = f2bf(x);
        unsigned short l = f2bf(x - __uint_as_float((u32)h << 16));
        wph[(size_t)tap * 524288 + id] = h;
        wph[4718592 + (size_t)tap * 524288 + id] = l;
    }
}

/* conv3 via MFMA, tap-major. PROVEN r4 version (399us, MfmaUtil 56, 0 confl):
   128oc x 128px block, 4 waves, 512-block 1D grid with bijective XCD remap
   (per-XCD X working set 9.2MB). SETTLED: r1 (32x32+W-reg), r2 (counted
   vmcnt), r5 (wide-wave 1/CU) all regressed; this 2-wave/SIMD 2-barrier
   structure is the local optimum. Do not touch. */
__global__ __launch_bounds__(256, 2) void k_conv3m(const unsigned short* __restrict__ xt,
                                                   const unsigned short* __restrict__ wp,
                                                   const float* __restrict__ bias,
                                                   const unsigned short* __restrict__ zst,
                                                   float* __restrict__ out) {
    const int bid = blockIdx.x;          /* 0..511 */
    const int xcd = bid & 7;
    const int kk  = bid >> 3;            /* 0..63 */
    const int ocg = kk & 3;
    const int y   = xcd * 16 + (kk >> 2);
    const int oc0 = ocg * 128;
    const int tid = threadIdx.x;
    const int lane = tid & 63;
    const int w    = tid >> 6;
    const int l15  = lane & 15;
    const int quad = lane >> 4;
    const int hoc  = w >> 1, hpx = w & 1;

    __shared__ __align__(16) unsigned short Lds[32768];   /* 64 KB */

    /* DMA slot geometry (per wave: 4 X slots + 4 W slots) */
    const int lg  = lane & 3;            /* LDS granule this lane fills  */
    const int lr  = lane >> 2;           /* row-within-16 this lane fills */

    const unsigned short* xsrc[4];
    int xstep[4];
    const unsigned short* wsrc[4];

    /* W sources: tap-linear, never redirected */
    int wp_pl[4], wp_ocr[4], wp_gs[4];
#pragma unroll
    for (int j = 0; j < 4; ++j) {
        int i = w + 4 * j;
        wp_pl[j]  = i >> 3;
        wp_ocr[j] = (i & 7) * 16 + lr;
        wp_gs[j]  = lg ^ ((wp_ocr[j] >> 1) & 3);
    }
    int xp_pl[4], xp_p[4], xp_gs[4];
#pragma unroll
    for (int j = 0; j < 4; ++j) {
        int i = w + 4 * j;
        xp_pl[j] = i >> 3;
        xp_p[j]  = (i & 7) * 16 + lr;
        xp_gs[j] = lg ^ ((xp_p[j] >> 1) & 3);
    }

    auto set_tap = [&](int tap) {
        int dy = tap / 3, dx = tap - dy * 3;
        int yy = y + dy - 1;
        bool yok = (yy >= 0) && (yy < HH);
#pragma unroll
        for (int j = 0; j < 4; ++j) {
            int x = dx - 1 + xp_p[j];
            bool ok = yok && (x >= 0) && (x < WW);
            xsrc[j] = ok ? xt + (size_t)xp_pl[j] * 16777216
                              + (size_t)(yy * WW + x) * 1024 + xp_gs[j] * 8
                         : zst + lg * 8;
            xstep[j] = ok ? 32 : 0;
        }
#pragma unroll
        for (int j = 0; j < 4; ++j)
            wsrc[j] = wp + (size_t)wp_pl[j] * 4718592 + (size_t)tap * 524288
                        + (size_t)(oc0 + wp_ocr[j]) * 1024 + wp_gs[j] * 8;
    };

    auto issue = [&](int sel) {
        const int bo = sel * 16384;
#pragma unroll
        for (int j = 0; j < 4; ++j) {
            gl_lds16(xsrc[j], &Lds[bo + (w + 4 * j) * 512]);
            xsrc[j] += xstep[j];
        }
#pragma unroll
        for (int j = 0; j < 4; ++j) {
            gl_lds16(wsrc[j], &Lds[bo + 8192 + (w + 4 * j) * 512]);
            wsrc[j] += 32;
        }
    };

    /* compute-side read bases: swizzle g identical for all og/nt (stride 16) */
    const int g  = quad ^ ((l15 >> 1) & 3);
    const int bB0 = (hpx * 64 + l15) * 32 + g * 8;
    const int bA0 = 8192 + (hoc * 64 + l15) * 32 + g * 8;

    f32x4 acc[4][4];
#pragma unroll
    for (int og = 0; og < 4; ++og)
#pragma unroll
        for (int nt = 0; nt < 4; ++nt) acc[og][nt] = (f32x4){0.f, 0.f, 0.f, 0.f};

    set_tap(0);
    issue(0);

    for (int s = 0; s < 288; ++s) {
        const int cur = s & 1;
        __syncthreads();        /* drains cur-buffer DMA (in flight one full
                                   stage) + all waves done with other buffer */
        if (s + 1 < 288) {
            int s1 = s + 1;
            if ((s1 & 31) == 0) set_tap(s1 >> 5);
            issue(s1 & 1);
        }

        const int bo = cur * 16384;
        s16x8 ah[4], al[4];
#pragma unroll
        for (int og = 0; og < 4; ++og) {
            ah[og] = *(const s16x8*)&Lds[bo + bA0 + og * 512];
            al[og] = *(const s16x8*)&Lds[bo + bA0 + 4096 + og * 512];
        }
#pragma unroll
        for (int nt = 0; nt < 4; ++nt) {
            const s16x8 bh = *(const s16x8*)&Lds[bo + bB0 + nt * 512];
            const s16x8 bl = *(const s16x8*)&Lds[bo + bB0 + 4096 + nt * 512];
#pragma unroll
            for (int og = 0; og < 4; ++og) {
                acc[og][nt] = __builtin_amdgcn_mfma_f32_16x16x32_bf16(ah[og], bh, acc[og][nt], 0, 0, 0);
                acc[og][nt] = __builtin_amdgcn_mfma_f32_16x16x32_bf16(ah[og], bl, acc[og][nt], 0, 0, 0);
                acc[og][nt] = __builtin_amdgcn_mfma_f32_16x16x32_bf16(al[og], bh, acc[og][nt], 0, 0, 0);
            }
        }
    }

    /* epilogue: D row(oc) = quad*4+reg, col(px) = l15 */
#pragma unroll
    for (int og = 0; og < 4; ++og) {
#pragma unroll
        for (int nt = 0; nt < 4; ++nt) {
#pragma unroll
            for (int rg = 0; rg < 4; ++rg) {
                const int oc = oc0 + hoc * 64 + og * 16 + quad * 4 + rg;
                const int px = hpx * 64 + nt * 16 + l15;
                float v = acc[og][nt][rg] + bias[oc];
                out[(size_t)oc * NPIX + y * WW + px] = fmaxf(v, 0.f);
            }
        }
    }
}

/* ---------------- fused 1x1 convs + pair softmax + pipeline-state init ---- */
__global__ __launch_bounds__(256) void k_conv1(const float* __restrict__ conv1,
                                               const float* __restrict__ wcls,
                                               const float* __restrict__ bcls,
                                               const float* __restrict__ wbox,
                                               const float* __restrict__ bboxb,
                                               float* __restrict__ out,
                                               u32* __restrict__ hist,
                                               u32* __restrict__ ctrl,
                                               u64* __restrict__ keys) {
    const int tid = threadIdx.x;
    {
        int gt = blockIdx.x * 256 + tid;
        hist[gt] = 0u;
        if (gt < 64) ctrl[gt] = 0u;
        if (gt < SORT_CAP) keys[gt] = ~0ULL;
    }
    const int og = tid >> 4, pg = tid & 15;
    const int px0 = blockIdx.x * 64;
    __shared__ __align__(16) float Wl[32][32];
    __shared__ __align__(16) float Xl[32][64];
    __shared__ float Sc[6][64];

    float a0[4] = {0, 0, 0, 0}, a1[4] = {0, 0, 0, 0};

    for (int cc = 0; cc < 16; ++cc) {
        {
            int u = tid;
            int row = (u * 4) >> 5;
            int col = (u * 4) & 31;
            float4 v;
            if (row < 6)       v = *(const float4*)(wcls + row * 512 + cc * 32 + col);
            else if (row < 30) v = *(const float4*)(wbox + (row - 6) * 512 + cc * 32 + col);
            else               v = make_float4(0.f, 0.f, 0.f, 0.f);
            *(float4*)&Wl[row][col] = v;
        }
        for (int u = tid; u < 512; u += 256) {
            int row = (u * 4) >> 6, col = (u * 4) & 63;
            *(float4*)&Xl[row][col] =
                *(const float4*)(conv1 + (size_t)(cc * 32 + row) * NPIX + px0 + col);
        }
        __syncthreads();
#pragma unroll
        for (int cp = 0; cp < 32; ++cp) {
            const float4 x = *(const float4*)&Xl[cp][pg * 4];
            const float w0 = Wl[og][cp];
            const float w1 = Wl[og + 16][cp];
            a0[0] = fmaf(w0, x.x, a0[0]); a0[1] = fmaf(w0, x.y, a0[1]);
            a0[2] = fmaf(w0, x.z, a0[2]); a0[3] = fmaf(w0, x.w, a0[3]);
            a1[0] = fmaf(w1, x.x, a1[0]); a1[1] = fmaf(w1, x.y, a1[1]);
            a1[2] = fmaf(w1, x.z, a1[2]); a1[3] = fmaf(w1, x.w, a1[3]);
        }
        __syncthreads();
    }
    const int pxb = px0 + pg * 4;
    if (og < 6) {
        const float bc = bcls[og];
#pragma unroll
        for (int kk = 0; kk < 4; ++kk) Sc[og][pg * 4 + kk] = a0[kk] + bc;
    } else {
        const float bb = bboxb[og - 6];
#pragma unroll
        for (int kk = 0; kk < 4; ++kk)
            out[OUT_BBOX + (size_t)(og - 6) * NPIX + pxb + kk] = a0[kk] + bb;
    }
    if (og + 16 < 30) {
        const float bb = bboxb[og + 10];
#pragma unroll
        for (int kk = 0; kk < 4; ++kk)
            out[OUT_BBOX + (size_t)(og + 10) * NPIX + pxb + kk] = a1[kk] + bb;
    }
    __syncthreads();
    if (og < 6) {
        const int pa = og < 3 ? og + 3 : og - 3;
#pragma unroll
        for (int kk = 0; kk < 4; ++kk) {
            const float s = Sc[og][pg * 4 + kk], sp = Sc[pa][pg * 4 + kk];
            out[OUT_PROB + (size_t)og * NPIX + pxb + kk] = 1.0f / (1.0f + expf(sp - s));
        }
    }
}

/* ---------------- anchor decode + clip + fused histogram ---------------- */
__global__ void k_decode(const float* __restrict__ out, const float* __restrict__ meta,
                         float4* __restrict__ boxes, float* __restrict__ scores,
                         u32* __restrict__ hist) {
#pragma clang fp contract(off)
    int t = blockIdx.x * blockDim.x + threadIdx.x;
    if (t >= NANCH) return;
    int a = t >> 14;
    int pix = t & 16383;
    int yc = pix >> 7, xc = pix & 127;
    int n = pix * 6 + a;
    float sc = out[OUT_PROB + (size_t)a * NPIX + pix];
    float d0 = out[OUT_BBOX + (size_t)(a * 4 + 0) * NPIX + pix];
    float d1 = out[OUT_BBOX + (size_t)(a * 4 + 1) * NPIX + pix];
    float d2 = out[OUT_BBOX + (size_t)(a * 4 + 2) * NPIX + pix];
    float d3 = out[OUT_BBOX + (size_t)(a * 4 + 3) * NPIX + pix];
    const float dims = (float)(16 << a);
    const float cxa = (xc + 0.5f) * 16.f;
    const float cya = (yc + 0.5f) * 16.f;
    float pcx = d0 * dims + cxa;
    float pcy = d1 * dims + cya;
    float pw  = expf(d2) * dims;
    float ph  = expf(d3) * dims;
    float imh = meta[0], imw = meta[1];
    float x1 = fminf(fmaxf(pcx - 0.5f * pw, 0.f), imw);
    float y1 = fminf(fmaxf(pcy - 0.5f * ph, 0.f), imh);
    float x2 = fminf(fmaxf(pcx + 0.5f * pw, 0.f), imw);
    float y2 = fminf(fmaxf(pcy + 0.5f * ph, 0.f), imh);
    boxes[n] = make_float4(x1, y1, x2, y2);
    scores[n] = sc;
    atomicAdd(&hist[__float_as_uint(sc) >> 16], 1u);
}

/* Parallel threshold select (r7, proven). */
__global__ __launch_bounds__(256) void k_select(const u32* __restrict__ hist,
                                                u32* __restrict__ ctrl) {
    __shared__ u32 S[256];
    __shared__ u32 T[256];
    __shared__ u32 wsb, wabove;
    const int tid = threadIdx.x;
    const int lane = tid & 63, wv = tid >> 6;
    for (int k = 0; k < 64; ++k) {
        int sb = wv * 64 + k;
        uint4 v = *(const uint4*)(hist + (size_t)sb * 256 + lane * 4);
        u32 p = v.x + v.y + v.z + v.w;
#pragma unroll
        for (int d = 1; d < 64; d <<= 1)
            p += (u32)__shfl_xor((int)p, d);
        if (lane == 0) S[sb] = p;
    }
    __syncthreads();
    T[tid] = S[tid];
    __syncthreads();
#pragma unroll
    for (int d = 1; d < 256; d <<= 1) {          /* inclusive suffix sum */
        u32 v2 = T[tid] + ((tid + d < 256) ? T[tid + d] : 0u);
        __syncthreads();
        T[tid] = v2;
        __syncthreads();
    }
    {
        u32 above = T[tid] - S[tid];
        if (above < KPRE && above + S[tid] >= KPRE) { wsb = (u32)tid; wabove = above; }
    }
    __syncthreads();
    const int sb = (int)wsb;
    const u32 h = hist[(size_t)sb * 256 + tid];
    T[tid] = h;
    __syncthreads();
#pragma unroll
    for (int d = 1; d < 256; d <<= 1) {
        u32 v2 = T[tid] + ((tid + d < 256) ? T[tid + d] : 0u);
        __syncthreads();
        T[tid] = v2;
        __syncthreads();
    }
    u32 acc = wabove + (T[tid] - h);             /* count strictly above bucket */
    if (acc < KPRE && acc + h >= KPRE) {
        ctrl[1] = (u32)(sb * 256 + tid);
        ctrl[2] = acc;
    }
}

__global__ void k_compact(const float* __restrict__ scores, u32* __restrict__ ctrl,
                          u64* __restrict__ keys) {
    int t = blockIdx.x * blockDim.x + threadIdx.x;
    if (t >= NANCH) return;
    u32 bits = __float_as_uint(scores[t]);
    if ((bits >> 16) >= ctrl[1]) {
        u32 pos = atomicAdd(&ctrl[0], 1u);
        if (pos < SORT_CAP) keys[pos] = ((u64)(~bits) << 32) | (u32)t;
    }
}

__global__ __launch_bounds__(1024) void k_sort_local(u64* __restrict__ keys) {
    __shared__ u64 lds[8192];
    const int tid = threadIdx.x;
    u64* g = keys + blockIdx.x * 8192;
    for (int u = tid; u < 8192; u += 1024) lds[u] = g[u];
    __syncthreads();
    for (int k = 2; k <= 8192; k <<= 1) {
        for (int j = k >> 1; j > 0; j >>= 1) {
            for (int u = tid; u < 4096; u += 1024) {
                int i = ((u & ~(j - 1)) << 1) | (u & (j - 1));
                int l = i | j;
                bool up = (i & k) == 0;
                u64 x = lds[i], y2 = lds[l];
                if ((x > y2) == up) { lds[i] = y2; lds[l] = x; }
            }
            __syncthreads();
        }
    }
    for (int u = tid; u < 8192; u += 1024) g[u] = lds[u];
}

/* merge the two sorted 8192-halves AND gather boxes/areas in one pass */
__global__ void k_mergegather(const u64* __restrict__ keys,
                              const float4* __restrict__ boxes,
                              float4* __restrict__ tb, float* __restrict__ areas) {
#pragma clang fp contract(off)
    int i = blockIdx.x * blockDim.x + threadIdx.x;
    if (i >= KPRE) return;
    const u64* A = keys;
    const u64* B = keys + 8192;
    int lo = i > 8192 ? i - 8192 : 0;
    int hi = i < 8192 ? i : 8192;
    while (lo < hi) {
        int a = (lo + hi) >> 1;
        if (A[a] < B[i - a - 1]) lo = a + 1; else hi = a;
    }
    int a = lo, b = i - lo;
    u64 va = (a < 8192) ? A[a] : ~0ULL;
    u64 vb = (b < 8192) ? B[b] : ~0ULL;
    u64 v = va < vb ? va : vb;
    u32 n = (u32)(v & 0xFFFFFFFFULL);
    float4 bx = boxes[n];
    tb[i] = bx;
    areas[i] = fmaxf(bx.z - bx.x, 0.f) * fmaxf(bx.w - bx.y, 0.f);
}

/* bitmap NMS precompute, upper-triangle only (see r4 note). Additionally
   stores diag[i] = row i's own-chunk word (Wd == i>>6) for the chunked scan. */
__global__ __launch_bounds__(256) void k_bitmap(const float4* __restrict__ tb,
                                                const float* __restrict__ areas,
                                                u64* __restrict__ suppr,
                                                u64* __restrict__ diag) {
#pragma clang fp contract(off)
    const int i = blockIdx.x;
    const int lane = threadIdx.x & 63;
    const int wv = threadIdx.x >> 6;
    const float4 bi = tb[i];
    const float ai = areas[i];
    const int w0 = i >> 6;
    for (int Wd = w0 + wv; Wd < RW; Wd += 4) {
        int j = Wd * 64 + lane;
        bool sup = false;
        if (j < KPRE) {
            float4 bj = tb[j];
            float iw = fmaxf(fminf(bi.z, bj.z) - fmaxf(bi.x, bj.x), 0.f);
            float ih = fmaxf(fminf(bi.w, bj.w) - fmaxf(bi.y, bj.y), 0.f);
            float inter = iw * ih;
            float denom = ((areas[j] + ai) - inter) + 1e-9f;
            sup = (inter / denom) > NMS_T;
        }
        u64 m = __ballot(sup);
        if (lane == 0) {
            suppr[(size_t)i * RW + Wd] = m;
            if (Wd == w0) diag[i] = m;
        }
    }
}

/* Chunked greedy scan (r6, proven) + fused ROI write (r7). */
__global__ void k_scan(const u64* __restrict__ suppr, const u64* __restrict__ diag,
                       const float4* __restrict__ tb, float* __restrict__ out) {
    const int lane = threadIdx.x;     /* 64 threads */
    __shared__ int keepL[KPOST];
    u64 a0 = (lane < 93) ? ~0ULL : (lane == 93 ? ((1ULL << 48) - 1) : 0ULL);
    const int w1 = lane + 64;
    u64 a1 = (w1 < 93) ? ~0ULL : (w1 == 93 ? ((1ULL << 48) - 1) : 0ULL);
    int kept = 0;
    u64 dv_cur = diag[lane];          /* chunk 0 diag, lane l = row l word 0 */
    for (int c = 0; c < 94 && kept < KPOST; ++c) {
        u64 dv_nxt = (c < 93) ? diag[(size_t)(c + 1) * 64 + lane] : 0ULL;
        u64 ac = (c < 64) ? (u64)__shfl((long long)a0, c)
                          : (u64)__shfl((long long)a1, c - 64);
        u64 m = ac;
        u64 keptMask = 0;
        while (m && kept < KPOST) {
            int b = __ffsll((long long)m) - 1;
            if (lane == 0) keepL[kept] = (c << 6) + b;
            kept++;
            keptMask |= (1ULL << b);
            u64 dv = (u64)__shfl((long long)dv_cur, b);
            m &= ~dv;
            m &= ~(1ULL << b);        /* self-advance (zero-area safe) */
        }
        if (keptMask && kept < KPOST + 64) {   /* apply rows to future words */
            u64 s0 = 0, s1 = 0;
            u64 km = keptMask;
            while (km) {
                int b = __ffsll((long long)km) - 1;
                km &= km - 1;
                const u64* row = suppr + (size_t)((c << 6) + b) * RW;
                u64 r0 = (lane > c) ? row[lane] : 0ULL;
                u64 r1 = (w1 > c && w1 < 94) ? row[w1] : 0ULL;
                s0 |= r0; s1 |= r1;
            }
            a0 &= ~s0; a1 &= ~s1;
        }
        dv_cur = dv_nxt;
    }
    __syncthreads();
    for (int r = lane; r < KPOST; r += 64) {
        float4 b = make_float4(0.f, 0.f, 0.f, 0.f);
        if (r < kept) b = tb[keepL[r]];
        out[r * 5 + 0] = 0.f;
        out[r * 5 + 1] = b.x;
        out[r * 5 + 2] = b.y;
        out[r * 5 + 3] = b.z;
        out[r * 5 + 4] = b.w;
    }
}

extern "C" void kernel_launch(void* const* d_in, const int* in_sizes, int n_in,
                              void* d_out, int out_size, void* d_ws, size_t ws_size,
                              hipStream_t stream) {
    (void)in_sizes; (void)n_in; (void)out_size; (void)ws_size;
    const float* x     = (const float*)d_in[0];
    const float* meta  = (const float*)d_in[1];
    const float* wc3   = (const float*)d_in[3];
    const float* bc3   = (const float*)d_in[4];
    const float* wcls  = (const float*)d_in[5];
    const float* bcls  = (const float*)d_in[6];
    const float* wbox  = (const float*)d_in[7];
    const float* bboxb = (const float*)d_in[8];
    float* out = (float*)d_out;
    char* ws = (char*)d_ws;

    float*  conv1  = (float*)(ws + WS_CONV1);
    float4* boxes  = (float4*)(ws + WS_BOXES);
    float*  scores = (float*)(ws + WS_SCORE);
    u64*    keys   = (u64*)(ws + WS_KEYS);
    float4* tb     = (float4*)(ws + WS_TB);
    float*  areas  = (float*)(ws + WS_AREA);
    u64*    suppr  = (u64*)(ws + WS_SUP);
    u32*    hist   = (u32*)(ws + WS_HIST);
    u32*    ctrl   = (u32*)(ws + WS_CTRL);
    u64*    diag   = (u64*)(ws + WS_DIAG);

    float* zstash = out;   /* 512B zeros; rewritten by k_scan at the end */

    unsigned short* xth = (unsigned short*)(ws + WS_XTH);
    unsigned short* wph = (unsigned short*)(ws + WS_WPH);
    k_xsplit<<<dim3(256, 16), 256, 0, stream>>>(x, xth);
    k_wpack<<<2048, 256, 0, stream>>>(wc3, wph, zstash);
    k_conv3m<<<512, 256, 0, stream>>>(xth, wph, bc3,
                                      (const unsigned short*)zstash, conv1);

    k_conv1<<<256, 256, 0, stream>>>(conv1, wcls, bcls, wbox, bboxb, out,
                                     hist, ctrl, keys);
    k_decode<<<384, 256, 0, stream>>>(out, meta, boxes, scores, hist);
    k_select<<<1, 256, 0, stream>>>(hist, ctrl);
    k_compact<<<384, 256, 0, stream>>>(scores, ctrl, keys);
    k_sort_local<<<2, 1024, 0, stream>>>(keys);
    k_mergegather<<<24, 256, 0, stream>>>(keys, boxes, tb, areas);
    k_bitmap<<<6000, 256, 0, stream>>>(tb, areas, suppr, diag);
    k_scan<<<1, 64, 0, stream>>>(suppr, diag, tb, out);
}

// Round 11
// 866.302 us; speedup vs baseline: 1.0246x; 1.0065x over previous
//
#include <hip/hip_runtime.h>
#include <math.h>

typedef unsigned int u32;
typedef unsigned long long u64;
typedef short s16x8 __attribute__((ext_vector_type(8)));
typedef float f32x4 __attribute__((ext_vector_type(4)));

#define HH 128
#define WW 128
#define NPIX (128*128)
#define NANCH (NPIX*6)
#define KPRE 6000
#define KPOST 300
#define SORT_CAP 16384
#define RW 96
#define NMS_T 0.7f

#define OUT_PROB 1500
#define OUT_BBOX (1500 + 98304)

/* ---------------- ws layout (bytes) ----------------
   [conv1 33.5M][Xth 33.5M|Xtl 33.5M][Wph 9.4M|Wpl 9.4M] = 119.5MB
   post-conv3 buffers alias offset 33.5MB. */
#define WS_CONV1 ((size_t)0)
#define WS_XTH   ((size_t)33554432)
#define WS_WPH   ((size_t)100663296)
#define WS_BOXES ((size_t)33554432)
#define WS_SCORE (WS_BOXES + 1572864)
#define WS_KEYS  (WS_SCORE + 393216)
#define WS_TB    (WS_KEYS + 131072)
#define WS_AREA  (WS_TB + 98304)
#define WS_SUP   (WS_AREA + 24576)
#define WS_HIST  (WS_SUP + 4718592)
#define WS_CTRL  (WS_HIST + 262144)
#define WS_KEEP  (WS_CTRL + 256)
#define WS_DIAG  (WS_KEEP + 1280)

__device__ __forceinline__ unsigned short f2bf(float x) {
    u32 b = __float_as_uint(x);
    u32 r = (b + 0x7FFFu + ((b >> 16) & 1u)) >> 16;
    return (unsigned short)r;
}

/* async global->LDS, 16B/lane: dest = wave-uniform base + lane*16 */
__device__ __forceinline__ void gl_lds16(const void* g, void* l) {
    __builtin_amdgcn_global_load_lds(
        (__attribute__((address_space(1))) const void*)g,
        (__attribute__((address_space(3))) void*)l,
        16, 0, 0);
}

/* fused prepass: blocks [0,4096) = X transpose+split; [4096,6144) = W pack.
   (Bodies verbatim from the proven k_xsplit / k_wpack; role branch only.) */
__global__ __launch_bounds__(256) void k_pre(const float* __restrict__ in,
                                             unsigned short* __restrict__ xth,
                                             const float* __restrict__ w,
                                             unsigned short* __restrict__ wph,
                                             float* __restrict__ zstash) {
    const int bid = blockIdx.x;
    const int t = threadIdx.x;
    __shared__ unsigned short Th[64][72];
    __shared__ unsigned short Tl[64][72];
    if (bid >= 4096) {                    /* ---- W pack role ---- */
        const int wb = bid - 4096;
        if (wb == 0 && t < 128) zstash[t] = 0.f;
        int id = wb * 256 + t;            /* 524288 = oc*1024 + c */
        int oc = id >> 10, c = id & 1023;
        const float* src = w + (size_t)oc * 9216 + c * 9;
#pragma unroll
        for (int tap = 0; tap < 9; ++tap) {
            float x = src[tap];
            unsigned short h = f2bf(x);
            unsigned short l = f2bf(x - __uint_as_float((u32)h << 16));
            wph[(size_t)tap * 524288 + id] = h;
            wph[4718592 + (size_t)tap * 524288 + id] = l;
        }
        return;
    }
    /* ---- X split role ---- */
    unsigned short* xtl = xth + 16777216;
    const int px0 = (bid & 255) * 64;
    const int c0  = (bid >> 8) * 64;
    const int r = t >> 4;
    const int p4 = (t & 15) * 4;
#pragma unroll
    for (int i = 0; i < 4; ++i) {
        int cr = r + 16 * i;
        float4 v = *(const float4*)(in + (size_t)(c0 + cr) * NPIX + px0 + p4);
        float vv[4] = {v.x, v.y, v.z, v.w};
#pragma unroll
        for (int k = 0; k < 4; ++k) {
            unsigned short h = f2bf(vv[k]);
            float hf = __uint_as_float((u32)h << 16);
            unsigned short l = f2bf(vv[k] - hf);
            Th[p4 + k][cr] = h;
            Tl[p4 + k][cr] = l;
        }
    }
    __syncthreads();
    const int p = t >> 2, q = t & 3;
    unsigned short* dh = xth + (size_t)(px0 + p) * 1024 + c0 + q * 16;
    unsigned short* dl = xtl + (size_t)(px0 + p) * 1024 + c0 + q * 16;
    *(uint4*)dh       = *(const uint4*)&Th[p][q * 16];
    *(uint4*)(dh + 8) = *(const uint4*)&Th[p][q * 16 + 8];
    *(uint4*)dl       = *(const uint4*)&Tl[p][q * 16];
    *(uint4*)(dl + 8) = *(const uint4*)&Tl[p][q * 16 + 8];
}

/* conv3 via MFMA, tap-major. PROVEN r4 version (399us, MfmaUtil 56, 0 confl):
   128oc x 128px block, 4 waves, 512-block 1D grid with bijective XCD remap
   (per-XCD X working set 9.2MB). SETTLED: r1 (32x32+W-reg), r2 (counted
   vmcnt), r5 (wide-wave 1/CU) all regressed; this 2-wave/SIMD 2-barrier
   structure is the local optimum. Do not touch. */
__global__ __launch_bounds__(256, 2) void k_conv3m(const unsigned short* __restrict__ xt,
                                                   const unsigned short* __restrict__ wp,
                                                   const float* __restrict__ bias,
                                                   const unsigned short* __restrict__ zst,
                                                   float* __restrict__ out) {
    const int bid = blockIdx.x;          /* 0..511 */
    const int xcd = bid & 7;
    const int kk  = bid >> 3;            /* 0..63 */
    const int ocg = kk & 3;
    const int y   = xcd * 16 + (kk >> 2);
    const int oc0 = ocg * 128;
    const int tid = threadIdx.x;
    const int lane = tid & 63;
    const int w    = tid >> 6;
    const int l15  = lane & 15;
    const int quad = lane >> 4;
    const int hoc  = w >> 1, hpx = w & 1;

    __shared__ __align__(16) unsigned short Lds[32768];   /* 64 KB */

    /* DMA slot geometry (per wave: 4 X slots + 4 W slots) */
    const int lg  = lane & 3;            /* LDS granule this lane fills  */
    const int lr  = lane >> 2;           /* row-within-16 this lane fills */

    const unsigned short* xsrc[4];
    int xstep[4];
    const unsigned short* wsrc[4];

    /* W sources: tap-linear, never redirected */
    int wp_pl[4], wp_ocr[4], wp_gs[4];
#pragma unroll
    for (int j = 0; j < 4; ++j) {
        int i = w + 4 * j;
        wp_pl[j]  = i >> 3;
        wp_ocr[j] = (i & 7) * 16 + lr;
        wp_gs[j]  = lg ^ ((wp_ocr[j] >> 1) & 3);
    }
    int xp_pl[4], xp_p[4], xp_gs[4];
#pragma unroll
    for (int j = 0; j < 4; ++j) {
        int i = w + 4 * j;
        xp_pl[j] = i >> 3;
        xp_p[j]  = (i & 7) * 16 + lr;
        xp_gs[j] = lg ^ ((xp_p[j] >> 1) & 3);
    }

    auto set_tap = [&](int tap) {
        int dy = tap / 3, dx = tap - dy * 3;
        int yy = y + dy - 1;
        bool yok = (yy >= 0) && (yy < HH);
#pragma unroll
        for (int j = 0; j < 4; ++j) {
            int x = dx - 1 + xp_p[j];
            bool ok = yok && (x >= 0) && (x < WW);
            xsrc[j] = ok ? xt + (size_t)xp_pl[j] * 16777216
                              + (size_t)(yy * WW + x) * 1024 + xp_gs[j] * 8
                         : zst + lg * 8;
            xstep[j] = ok ? 32 : 0;
        }
#pragma unroll
        for (int j = 0; j < 4; ++j)
            wsrc[j] = wp + (size_t)wp_pl[j] * 4718592 + (size_t)tap * 524288
                        + (size_t)(oc0 + wp_ocr[j]) * 1024 + wp_gs[j] * 8;
    };

    auto issue = [&](int sel) {
        const int bo = sel * 16384;
#pragma unroll
        for (int j = 0; j < 4; ++j) {
            gl_lds16(xsrc[j], &Lds[bo + (w + 4 * j) * 512]);
            xsrc[j] += xstep[j];
        }
#pragma unroll
        for (int j = 0; j < 4; ++j) {
            gl_lds16(wsrc[j], &Lds[bo + 8192 + (w + 4 * j) * 512]);
            wsrc[j] += 32;
        }
    };

    /* compute-side read bases: swizzle g identical for all og/nt (stride 16) */
    const int g  = quad ^ ((l15 >> 1) & 3);
    const int bB0 = (hpx * 64 + l15) * 32 + g * 8;
    const int bA0 = 8192 + (hoc * 64 + l15) * 32 + g * 8;

    f32x4 acc[4][4];
#pragma unroll
    for (int og = 0; og < 4; ++og)
#pragma unroll
        for (int nt = 0; nt < 4; ++nt) acc[og][nt] = (f32x4){0.f, 0.f, 0.f, 0.f};

    set_tap(0);
    issue(0);

    for (int s = 0; s < 288; ++s) {
        const int cur = s & 1;
        __syncthreads();        /* drains cur-buffer DMA (in flight one full
                                   stage) + all waves done with other buffer */
        if (s + 1 < 288) {
            int s1 = s + 1;
            if ((s1 & 31) == 0) set_tap(s1 >> 5);
            issue(s1 & 1);
        }

        const int bo = cur * 16384;
        s16x8 ah[4], al[4];
#pragma unroll
        for (int og = 0; og < 4; ++og) {
            ah[og] = *(const s16x8*)&Lds[bo + bA0 + og * 512];
            al[og] = *(const s16x8*)&Lds[bo + bA0 + 4096 + og * 512];
        }
#pragma unroll
        for (int nt = 0; nt < 4; ++nt) {
            const s16x8 bh = *(const s16x8*)&Lds[bo + bB0 + nt * 512];
            const s16x8 bl = *(const s16x8*)&Lds[bo + bB0 + 4096 + nt * 512];
#pragma unroll
            for (int og = 0; og < 4; ++og) {
                acc[og][nt] = __builtin_amdgcn_mfma_f32_16x16x32_bf16(ah[og], bh, acc[og][nt], 0, 0, 0);
                acc[og][nt] = __builtin_amdgcn_mfma_f32_16x16x32_bf16(ah[og], bl, acc[og][nt], 0, 0, 0);
                acc[og][nt] = __builtin_amdgcn_mfma_f32_16x16x32_bf16(al[og], bh, acc[og][nt], 0, 0, 0);
            }
        }
    }

    /* epilogue: D row(oc) = quad*4+reg, col(px) = l15 */
#pragma unroll
    for (int og = 0; og < 4; ++og) {
#pragma unroll
        for (int nt = 0; nt < 4; ++nt) {
#pragma unroll
            for (int rg = 0; rg < 4; ++rg) {
                const int oc = oc0 + hoc * 64 + og * 16 + quad * 4 + rg;
                const int px = hpx * 64 + nt * 16 + l15;
                float v = acc[og][nt][rg] + bias[oc];
                out[(size_t)oc * NPIX + y * WW + px] = fmaxf(v, 0.f);
            }
        }
    }
}

/* init (after conv3m; targets alias the now-dead X staging region) */
__global__ void k_init(u32* __restrict__ hist, u32* __restrict__ ctrl,
                       u64* __restrict__ keys) {
    int t = blockIdx.x * blockDim.x + threadIdx.x;   /* 65536 exactly */
    hist[t] = 0u;
    if (t < 64) ctrl[t] = 0u;
    if (t < SORT_CAP) keys[t] = ~0ULL;
}

/* ---------------- fused 1x1 convs + pair softmax + DECODE (r11) ----------
   decode fused: this block computes every prob/bbox value its 64 px need,
   so stage bbox (24x64) and prob (6x64) in LDS and decode the block's 384
   boxes here instead of re-reading 12.6MB in a separate launch. Decode math
   in a contract(off) scope, operands bit-identical to the stored f32 values
   the old k_decode read back -> identical boxes/scores/hist. */
__global__ __launch_bounds__(256) void k_conv1(const float* __restrict__ conv1,
                                               const float* __restrict__ wcls,
                                               const float* __restrict__ bcls,
                                               const float* __restrict__ wbox,
                                               const float* __restrict__ bboxb,
                                               const float* __restrict__ meta,
                                               float* __restrict__ out,
                                               float4* __restrict__ boxes,
                                               float* __restrict__ scores,
                                               u32* __restrict__ hist) {
    const int tid = threadIdx.x;
    const int og = tid >> 4, pg = tid & 15;
    const int px0 = blockIdx.x * 64;
    __shared__ __align__(16) float Wl[32][32];
    __shared__ __align__(16) float Xl[32][64];
    __shared__ float Sc[6][64];
    __shared__ float Bb[24][64];
    __shared__ float Pr[6][64];

    float a0[4] = {0, 0, 0, 0}, a1[4] = {0, 0, 0, 0};

    for (int cc = 0; cc < 16; ++cc) {
        {
            int u = tid;
            int row = (u * 4) >> 5;
            int col = (u * 4) & 31;
            float4 v;
            if (row < 6)       v = *(const float4*)(wcls + row * 512 + cc * 32 + col);
            else if (row < 30) v = *(const float4*)(wbox + (row - 6) * 512 + cc * 32 + col);
            else               v = make_float4(0.f, 0.f, 0.f, 0.f);
            *(float4*)&Wl[row][col] = v;
        }
        for (int u = tid; u < 512; u += 256) {
            int row = (u * 4) >> 6, col = (u * 4) & 63;
            *(float4*)&Xl[row][col] =
                *(const float4*)(conv1 + (size_t)(cc * 32 + row) * NPIX + px0 + col);
        }
        __syncthreads();
#pragma unroll
        for (int cp = 0; cp < 32; ++cp) {
            const float4 x = *(const float4*)&Xl[cp][pg * 4];
            const float w0 = Wl[og][cp];
            const float w1 = Wl[og + 16][cp];
            a0[0] = fmaf(w0, x.x, a0[0]); a0[1] = fmaf(w0, x.y, a0[1]);
            a0[2] = fmaf(w0, x.z, a0[2]); a0[3] = fmaf(w0, x.w, a0[3]);
            a1[0] = fmaf(w1, x.x, a1[0]); a1[1] = fmaf(w1, x.y, a1[1]);
            a1[2] = fmaf(w1, x.z, a1[2]); a1[3] = fmaf(w1, x.w, a1[3]);
        }
        __syncthreads();
    }
    const int pxb = px0 + pg * 4;
    if (og < 6) {
        const float bc = bcls[og];
#pragma unroll
        for (int kk = 0; kk < 4; ++kk) Sc[og][pg * 4 + kk] = a0[kk] + bc;
    } else {
        const float bb = bboxb[og - 6];
#pragma unroll
        for (int kk = 0; kk < 4; ++kk) {
            const float v = a0[kk] + bb;
            out[OUT_BBOX + (size_t)(og - 6) * NPIX + pxb + kk] = v;
            Bb[og - 6][pg * 4 + kk] = v;
        }
    }
    if (og + 16 < 30) {
        const float bb = bboxb[og + 10];
#pragma unroll
        for (int kk = 0; kk < 4; ++kk) {
            const float v = a1[kk] + bb;
            out[OUT_BBOX + (size_t)(og + 10) * NPIX + pxb + kk] = v;
            Bb[og + 10][pg * 4 + kk] = v;
        }
    }
    __syncthreads();
    if (og < 6) {
        const int pa = og < 3 ? og + 3 : og - 3;
#pragma unroll
        for (int kk = 0; kk < 4; ++kk) {
            const float s = Sc[og][pg * 4 + kk], sp = Sc[pa][pg * 4 + kk];
            const float pv = 1.0f / (1.0f + expf(sp - s));
            out[OUT_PROB + (size_t)og * NPIX + pxb + kk] = pv;
            Pr[og][pg * 4 + kk] = pv;
        }
    }
    __syncthreads();
    {   /* ---- fused anchor decode + clip + histogram ---- */
#pragma clang fp contract(off)
        const float imh = meta[0], imw = meta[1];
        for (int idx = tid; idx < 384; idx += 256) {
            const int a = idx >> 6, p = idx & 63;
            const int pix = px0 + p;
            const int yc = pix >> 7, xc = pix & 127;
            const int n = pix * 6 + a;
            float sc = Pr[a][p];
            float d0 = Bb[a * 4 + 0][p];
            float d1 = Bb[a * 4 + 1][p];
            float d2 = Bb[a * 4 + 2][p];
            float d3 = Bb[a * 4 + 3][p];
            const float dims = (float)(16 << a);
            const float cxa = (xc + 0.5f) * 16.f;
            const float cya = (yc + 0.5f) * 16.f;
            float pcx = d0 * dims + cxa;
            float pcy = d1 * dims + cya;
            float pw  = expf(d2) * dims;
            float ph  = expf(d3) * dims;
            float x1 = fminf(fmaxf(pcx - 0.5f * pw, 0.f), imw);
            float y1 = fminf(fmaxf(pcy - 0.5f * ph, 0.f), imh);
            float x2 = fminf(fmaxf(pcx + 0.5f * pw, 0.f), imw);
            float y2 = fminf(fmaxf(pcy + 0.5f * ph, 0.f), imh);
            boxes[n] = make_float4(x1, y1, x2, y2);
            scores[n] = sc;
            atomicAdd(&hist[__float_as_uint(sc) >> 16], 1u);
        }
    }
}

/* Parallel threshold select (r7, proven). */
__global__ __launch_bounds__(256) void k_select(const u32* __restrict__ hist,
                                                u32* __restrict__ ctrl) {
    __shared__ u32 S[256];
    __shared__ u32 T[256];
    __shared__ u32 wsb, wabove;
    const int tid = threadIdx.x;
    const int lane = tid & 63, wv = tid >> 6;
    for (int k = 0; k < 64; ++k) {
        int sb = wv * 64 + k;
        uint4 v = *(const uint4*)(hist + (size_t)sb * 256 + lane * 4);
        u32 p = v.x + v.y + v.z + v.w;
#pragma unroll
        for (int d = 1; d < 64; d <<= 1)
            p += (u32)__shfl_xor((int)p, d);
        if (lane == 0) S[sb] = p;
    }
    __syncthreads();
    T[tid] = S[tid];
    __syncthreads();
#pragma unroll
    for (int d = 1; d < 256; d <<= 1) {          /* inclusive suffix sum */
        u32 v2 = T[tid] + ((tid + d < 256) ? T[tid + d] : 0u);
        __syncthreads();
        T[tid] = v2;
        __syncthreads();
    }
    {
        u32 above = T[tid] - S[tid];
        if (above < KPRE && above + S[tid] >= KPRE) { wsb = (u32)tid; wabove = above; }
    }
    __syncthreads();
    const int sb = (int)wsb;
    const u32 h = hist[(size_t)sb * 256 + tid];
    T[tid] = h;
    __syncthreads();
#pragma unroll
    for (int d = 1; d < 256; d <<= 1) {
        u32 v2 = T[tid] + ((tid + d < 256) ? T[tid + d] : 0u);
        __syncthreads();
        T[tid] = v2;
        __syncthreads();
    }
    u32 acc = wabove + (T[tid] - h);             /* count strictly above bucket */
    if (acc < KPRE && acc + h >= KPRE) {
        ctrl[1] = (u32)(sb * 256 + tid);
        ctrl[2] = acc;
    }
}

__global__ void k_compact(const float* __restrict__ scores, u32* __restrict__ ctrl,
                          u64* __restrict__ keys) {
    int t = blockIdx.x * blockDim.x + threadIdx.x;
    if (t >= NANCH) return;
    u32 bits = __float_as_uint(scores[t]);
    if ((bits >> 16) >= ctrl[1]) {
        u32 pos = atomicAdd(&ctrl[0], 1u);
        if (pos < SORT_CAP) keys[pos] = ((u64)(~bits) << 32) | (u32)t;
    }
}

__global__ __launch_bounds__(1024) void k_sort_local(u64* __restrict__ keys) {
    __shared__ u64 lds[8192];
    const int tid = threadIdx.x;
    u64* g = keys + blockIdx.x * 8192;
    for (int u = tid; u < 8192; u += 1024) lds[u] = g[u];
    __syncthreads();
    for (int k = 2; k <= 8192; k <<= 1) {
        for (int j = k >> 1; j > 0; j >>= 1) {
            for (int u = tid; u < 4096; u += 1024) {
                int i = ((u & ~(j - 1)) << 1) | (u & (j - 1));
                int l = i | j;
                bool up = (i & k) == 0;
                u64 x = lds[i], y2 = lds[l];
                if ((x > y2) == up) { lds[i] = y2; lds[l] = x; }
            }
            __syncthreads();
        }
    }
    for (int u = tid; u < 8192; u += 1024) g[u] = lds[u];
}

/* merge the two sorted 8192-halves AND gather boxes/areas in one pass */
__global__ void k_mergegather(const u64* __restrict__ keys,
                              const float4* __restrict__ boxes,
                              float4* __restrict__ tb, float* __restrict__ areas) {
#pragma clang fp contract(off)
    int i = blockIdx.x * blockDim.x + threadIdx.x;
    if (i >= KPRE) return;
    const u64* A = keys;
    const u64* B = keys + 8192;
    int lo = i > 8192 ? i - 8192 : 0;
    int hi = i < 8192 ? i : 8192;
    while (lo < hi) {
        int a = (lo + hi) >> 1;
        if (A[a] < B[i - a - 1]) lo = a + 1; else hi = a;
    }
    int a = lo, b = i - lo;
    u64 va = (a < 8192) ? A[a] : ~0ULL;
    u64 vb = (b < 8192) ? B[b] : ~0ULL;
    u64 v = va < vb ? va : vb;
    u32 n = (u32)(v & 0xFFFFFFFFULL);
    float4 bx = boxes[n];
    tb[i] = bx;
    areas[i] = fmaxf(bx.z - bx.x, 0.f) * fmaxf(bx.w - bx.y, 0.f);
}

/* bitmap NMS precompute, upper-triangle only (see r4 note). Additionally
   stores diag[i] = row i's own-chunk word (Wd == i>>6) for the chunked scan. */
__global__ __launch_bounds__(256) void k_bitmap(const float4* __restrict__ tb,
                                                const float* __restrict__ areas,
                                                u64* __restrict__ suppr,
                                                u64* __restrict__ diag) {
#pragma clang fp contract(off)
    const int i = blockIdx.x;
    const int lane = threadIdx.x & 63;
    const int wv = threadIdx.x >> 6;
    const float4 bi = tb[i];
    const float ai = areas[i];
    const int w0 = i >> 6;
    for (int Wd = w0 + wv; Wd < RW; Wd += 4) {
        int j = Wd * 64 + lane;
        bool sup = false;
        if (j < KPRE) {
            float4 bj = tb[j];
            float iw = fmaxf(fminf(bi.z, bj.z) - fmaxf(bi.x, bj.x), 0.f);
            float ih = fmaxf(fminf(bi.w, bj.w) - fmaxf(bi.y, bj.y), 0.f);
            float inter = iw * ih;
            float denom = ((areas[j] + ai) - inter) + 1e-9f;
            sup = (inter / denom) > NMS_T;
        }
        u64 m = __ballot(sup);
        if (lane == 0) {
            suppr[(size_t)i * RW + Wd] = m;
            if (Wd == w0) diag[i] = m;
        }
    }
}

/* Chunked greedy scan (r6, proven) + fused ROI write (r7). */
__global__ void k_scan(const u64* __restrict__ suppr, const u64* __restrict__ diag,
                       const float4* __restrict__ tb, float* __restrict__ out) {
    const int lane = threadIdx.x;     /* 64 threads */
    __shared__ int keepL[KPOST];
    u64 a0 = (lane < 93) ? ~0ULL : (lane == 93 ? ((1ULL << 48) - 1) : 0ULL);
    const int w1 = lane + 64;
    u64 a1 = (w1 < 93) ? ~0ULL : (w1 == 93 ? ((1ULL << 48) - 1) : 0ULL);
    int kept = 0;
    u64 dv_cur = diag[lane];          /* chunk 0 diag, lane l = row l word 0 */
    for (int c = 0; c < 94 && kept < KPOST; ++c) {
        u64 dv_nxt = (c < 93) ? diag[(size_t)(c + 1) * 64 + lane] : 0ULL;
        u64 ac = (c < 64) ? (u64)__shfl((long long)a0, c)
                          : (u64)__shfl((long long)a1, c - 64);
        u64 m = ac;
        u64 keptMask = 0;
        while (m && kept < KPOST) {
            int b = __ffsll((long long)m) - 1;
            if (lane == 0) keepL[kept] = (c << 6) + b;
            kept++;
            keptMask |= (1ULL << b);
            u64 dv = (u64)__shfl((long long)dv_cur, b);
            m &= ~dv;
            m &= ~(1ULL << b);        /* self-advance (zero-area safe) */
        }
        if (keptMask && kept < KPOST + 64) {   /* apply rows to future words */
            u64 s0 = 0, s1 = 0;
            u64 km = keptMask;
            while (km) {
                int b = __ffsll((long long)km) - 1;
                km &= km - 1;
                const u64* row = suppr + (size_t)((c << 6) + b) * RW;
                u64 r0 = (lane > c) ? row[lane] : 0ULL;
                u64 r1 = (w1 > c && w1 < 94) ? row[w1] : 0ULL;
                s0 |= r0; s1 |= r1;
            }
            a0 &= ~s0; a1 &= ~s1;
        }
        dv_cur = dv_nxt;
    }
    __syncthreads();
    for (int r = lane; r < KPOST; r += 64) {
        float4 b = make_float4(0.f, 0.f, 0.f, 0.f);
        if (r < kept) b = tb[keepL[r]];
        out[r * 5 + 0] = 0.f;
        out[r * 5 + 1] = b.x;
        out[r * 5 + 2] = b.y;
        out[r * 5 + 3] = b.z;
        out[r * 5 + 4] = b.w;
    }
}

extern "C" void kernel_launch(void* const* d_in, const int* in_sizes, int n_in,
                              void* d_out, int out_size, void* d_ws, size_t ws_size,
                              hipStream_t stream) {
    (void)in_sizes; (void)n_in; (void)out_size; (void)ws_size;
    const float* x     = (const float*)d_in[0];
    const float* meta  = (const float*)d_in[1];
    const float* wc3   = (const float*)d_in[3];
    const float* bc3   = (const float*)d_in[4];
    const float* wcls  = (const float*)d_in[5];
    const float* bcls  = (const float*)d_in[6];
    const float* wbox  = (const float*)d_in[7];
    const float* bboxb = (const float*)d_in[8];
    float* out = (float*)d_out;
    char* ws = (char*)d_ws;

    float*  conv1  = (float*)(ws + WS_CONV1);
    float4* boxes  = (float4*)(ws + WS_BOXES);
    float*  scores = (float*)(ws + WS_SCORE);
    u64*    keys   = (u64*)(ws + WS_KEYS);
    float4* tb     = (float4*)(ws + WS_TB);
    float*  areas  = (float*)(ws + WS_AREA);
    u64*    suppr  = (u64*)(ws + WS_SUP);
    u32*    hist   = (u32*)(ws + WS_HIST);
    u32*    ctrl   = (u32*)(ws + WS_CTRL);
    u64*    diag   = (u64*)(ws + WS_DIAG);

    float* zstash = out;   /* 512B zeros; rewritten by k_scan at the end */

    unsigned short* xth = (unsigned short*)(ws + WS_XTH);
    unsigned short* wph = (unsigned short*)(ws + WS_WPH);

    k_pre<<<6144, 256, 0, stream>>>(x, xth, wc3, wph, zstash);
    k_conv3m<<<512, 256, 0, stream>>>(xth, wph, bc3,
                                      (const unsigned short*)zstash, conv1);
    k_init<<<256, 256, 0, stream>>>(hist, ctrl, keys);
    k_conv1<<<256, 256, 0, stream>>>(conv1, wcls, bcls, wbox, bboxb, meta,
                                     out, boxes, scores, hist);
    k_select<<<1, 256, 0, stream>>>(hist, ctrl);
    k_compact<<<384, 256, 0, stream>>>(scores, ctrl, keys);
    k_sort_local<<<2, 1024, 0, stream>>>(keys);
    k_mergegather<<<24, 256, 0, stream>>>(keys, boxes, tb, areas);
    k_bitmap<<<6000, 256, 0, stream>>>(tb, areas, suppr, diag);
    k_scan<<<1, 64, 0, stream>>>(suppr, diag, tb, out);
}